// Round 11
// baseline (310.571 us; speedup 1.0000x reference)
//
#include <hip/hip_runtime.h>
#include <hip/hip_bf16.h>
#include <math.h>

#define S_LEN 2048
#define B_SZ 4
#define NH 16
#define HD 64
#define C_DIM 1024
#define OUT_DIM 1024

static constexpr size_t BHSD = (size_t)B_SZ * NH * S_LEN * HD; // 8,388,608
#define QSCALE 0.18033688011112042f   /* 0.125 * log2(e): scores in log2 domain */

typedef __attribute__((ext_vector_type(8))) short v8bf;
typedef __attribute__((ext_vector_type(4))) float v4f;
typedef __attribute__((ext_vector_type(4))) unsigned short v4us;

__device__ inline unsigned short f2bf(float x) {
    unsigned u = __float_as_uint(x);
    return (unsigned short)((u + 0x7fffu + ((u >> 16) & 1u)) >> 16);  // RNE
}
__device__ inline float bf2f(unsigned short h) {
    return __uint_as_float(((unsigned)h) << 16);
}
__device__ inline unsigned short cvt_bf(float x) {
    __hip_bfloat16 hb = __float2bfloat16(x);
    return reinterpret_cast<unsigned short&>(hb);
}

// ---------------- Kernel 0a: f32 -> (hi,lo) bf16 split (weights) ----------------
__global__ __launch_bounds__(256)
void cvt_hl_kernel(const float* __restrict__ src, unsigned short* __restrict__ hi,
                   unsigned short* __restrict__ lo, int n4)
{
    int i = blockIdx.x * 256 + threadIdx.x;
    if (i >= n4) return;
    float4 v = reinterpret_cast<const float4*>(src)[i];
    float x[4] = {v.x, v.y, v.z, v.w};
    v4us h, l;
#pragma unroll
    for (int j = 0; j < 4; ++j) {
        unsigned short hh = f2bf(x[j]);
        h[j] = hh;
        l[j] = f2bf(x[j] - bf2f(hh));
    }
    reinterpret_cast<v4us*>(hi)[i] = h;
    reinterpret_cast<v4us*>(lo)[i] = l;
}

// ---------------- Kernel 0b: f32 -> bf16 (activations) ----------------
__global__ __launch_bounds__(256)
void cvt_hi_kernel(const float* __restrict__ src, unsigned short* __restrict__ hi, int n4)
{
    int i = blockIdx.x * 256 + threadIdx.x;
    if (i >= n4) return;
    float4 v = reinterpret_cast<const float4*>(src)[i];
    float x[4] = {v.x, v.y, v.z, v.w};
    v4us h;
#pragma unroll
    for (int j = 0; j < 4; ++j) h[j] = f2bf(x[j]);
    reinterpret_cast<v4us*>(hi)[i] = h;
}

// ---------------- 2-term split-bf16 mainloop: 128x128 tile, ring-3, counted vmcnt ----------------
// A = weights (hi+lo, 128 n-rows), B = activations (hi, 128 m-rows), BK=32.
// 4 waves (256 thr), wave = 64m x 64n (wm=w>>1, wn=w&1), acc[4][4], 32 MFMA/K-step/wave.
// LDS: ring-3 x (SA 16KB + SB 8KB) = 72KB -> 2 blocks/CU: cross-block TLP hides the
// read->MFMA serialization (m114). One barrier per K-step; gate = counted vmcnt(6)
// (prefetch distance 2 -> loads never drain in-loop).
__device__ __forceinline__ void split2_mainloop_128(
    const unsigned short* __restrict__ Ahi, const unsigned short* __restrict__ Alo,
    const unsigned short* __restrict__ Bhi,
    int an0, int bm0, unsigned short* SA, unsigned short* SB, v4f acc[4][4])
{
    constexpr int K = 1024;
    constexpr int NT = K / 32;
    const int t = threadIdx.x;
    const int lane = t & 63;
    const int w = t >> 6;            // 0..3
    const int wm = w >> 1;           // 0..1
    const int wn = w & 1;            // 0..1
    const int lr = lane & 15, lg = lane >> 4;

    auto CHUNK = [&](int kt, int bf, int u) {
        const int k0 = kt * 32;
        const int c = w * 6 + u;     // 0..23 wave-uniform chunk id
        const unsigned short* src;
        unsigned short* dst;
        if (c < 16) {                // A: 8 rt-subtiles x (hi,lo)
            int rt = c >> 1, par = c & 1;
            src = (par ? Alo : Ahi) + (size_t)(an0 + rt * 16 + lr) * K + k0 + lg * 8;
            dst = SA + bf * 8192 + par * 4096 + rt * 512;
        } else {                     // B: 8 rt-subtiles, hi only
            int rt = c - 16;
            src = Bhi + (size_t)(bm0 + rt * 16 + lr) * K + k0 + lg * 8;
            dst = SB + bf * 4096 + rt * 512;
        }
        __builtin_amdgcn_global_load_lds(
            (const __attribute__((address_space(1))) unsigned int*)src,
            (__attribute__((address_space(3))) unsigned int*)dst, 16, 0, 0);
    };
    auto STAGE_ALL = [&](int kt, int bf) {
#pragma unroll
        for (int u = 0; u < 6; ++u) CHUNK(kt, bf, u);
    };

    STAGE_ALL(0, 0);
    STAGE_ALL(1, 1);                 // 12 loads/lane outstanding

    for (int kt = 0; kt < NT; ++kt) {
        const int bf = kt % 3;
        // ring gate: stage(kt) landed (stage(kt+1) may stay in flight)
        if (kt + 1 < NT) { asm volatile("s_waitcnt vmcnt(6)" ::: "memory"); }
        else             { asm volatile("s_waitcnt vmcnt(0)" ::: "memory"); }
        __builtin_amdgcn_s_barrier();
        __builtin_amdgcn_sched_barrier(0);

        if (kt + 2 < NT) STAGE_ALL(kt + 2, (kt + 2) % 3);   // buf readers passed barrier at kt-1

        const unsigned short* sa = SA + bf * 8192;
        const unsigned short* sb = SB + bf * 4096;
        v8bf ah[4], al[4], bh[4];
#pragma unroll
        for (int i = 0; i < 4; ++i) {
            ah[i] = *reinterpret_cast<const v8bf*>(sa + (wn * 4 + i) * 512 + lane * 8);
            al[i] = *reinterpret_cast<const v8bf*>(sa + 4096 + (wn * 4 + i) * 512 + lane * 8);
            bh[i] = *reinterpret_cast<const v8bf*>(sb + (wm * 4 + i) * 512 + lane * 8);
        }
        __builtin_amdgcn_s_setprio(1);
#pragma unroll
        for (int q = 0; q < 4; ++q) {
#pragma unroll
            for (int nt = 0; nt < 4; ++nt)
                acc[q][nt] = __builtin_amdgcn_mfma_f32_16x16x32_bf16(ah[nt], bh[q], acc[q][nt], 0, 0, 0);
#pragma unroll
            for (int nt = 0; nt < 4; ++nt)
                acc[q][nt] = __builtin_amdgcn_mfma_f32_16x16x32_bf16(al[nt], bh[q], acc[q][nt], 0, 0, 0);
        }
        __builtin_amdgcn_s_setprio(0);
        // no trailing barrier: next iteration opens with gate
    }
}

// ---------------- Kernel 1: QKV projection (2-term, 128x128, 2 blocks/CU) ----------------
__global__ __launch_bounds__(256, 2)
void qkv_gemm_mfma(const unsigned short* __restrict__ Whi, const unsigned short* __restrict__ Wlo,
                   const unsigned short* __restrict__ Xhi, const float* __restrict__ bias,
                   unsigned short* __restrict__ qb, unsigned short* __restrict__ kb,
                   unsigned short* __restrict__ vb)
{
    __shared__ __align__(16) unsigned short SA[3 * 8192];    // 48 KB
    __shared__ __align__(16) unsigned short SB[3 * 4096];    // 24 KB
    const v4f zero4 = {0.f, 0.f, 0.f, 0.f};
    v4f acc[4][4];
#pragma unroll
    for (int i = 0; i < 4; ++i)
#pragma unroll
        for (int j = 0; j < 4; ++j) acc[i][j] = zero4;

    const int bm0 = blockIdx.x * 128;
    const int an0 = blockIdx.y * 128;
    split2_mainloop_128(Whi, Wlo, Xhi, an0, bm0, SA, SB, acc);

    const int t = threadIdx.x;
    const int lane = t & 63;
    const int w = t >> 6;
    const int wm = w >> 1, wn = w & 1;
    const int lr = lane & 15, lg = lane >> 4;
    const int nbase = an0 + wn * 64;
    const int mbase = bm0 + wm * 64;

#pragma unroll
    for (int nt = 0; nt < 4; ++nt) {
        const int n0 = nbase + nt * 16 + lg * 4;
        const float4 b4 = *reinterpret_cast<const float4*>(bias + n0);
        const float bv[4] = {b4.x, b4.y, b4.z, b4.w};
        const int tsel = n0 >> 10;
        const int np = n0 & 1023;
        const int hh = np >> 6;
        const int dd = np & 63;
#pragma unroll
        for (int mt = 0; mt < 4; ++mt) {
            const int m = mbase + mt * 16 + lr;
            const int s = m >> 2, b = m & 3;
            float vals[4];
#pragma unroll
            for (int r = 0; r < 4; ++r) vals[r] = acc[mt][nt][r] + bv[r];
            if (tsel == 0) {
                v4us h;
#pragma unroll
                for (int r = 0; r < 4; ++r) h[r] = f2bf(vals[r] * QSCALE);
                *reinterpret_cast<v4us*>(qb + ((size_t)(b * NH + hh) * S_LEN + s) * HD + dd) = h;
            } else if (tsel == 1) {
                v4us h;
#pragma unroll
                for (int r = 0; r < 4; ++r) h[r] = f2bf(vals[r]);
                *reinterpret_cast<v4us*>(kb + ((size_t)(b * NH + hh) * S_LEN + s) * HD + dd) = h;
            } else {
#pragma unroll
                for (int r = 0; r < 4; ++r)
                    vb[((size_t)(b * NH + hh) * HD + dd + r) * S_LEN + s] = f2bf(vals[r]);
            }
        }
    }
}

// ---------------- Kernel 2: flash attention — bf16 QK^T, swapped operands ----------------
__global__ __launch_bounds__(256, 3)
void attn_kernel(const unsigned short* __restrict__ qb, const unsigned short* __restrict__ kb,
                 const unsigned short* __restrict__ vb, unsigned short* __restrict__ avh)
{
    __shared__ __align__(16) unsigned short SM[2][8192];   // KB@0 (8x512), VT@4096 (8x512)
    __shared__ __align__(16) unsigned short PL[4][32 * 64];  // per-wave P, XOR-swizzled

    const int t = threadIdx.x;
    const int lane = t & 63;
    const int w = t >> 6;
    const int lr = lane & 15;
    const int lg = lane >> 4;
    const int id = blockIdx.x;
    const int bh = id & 63;           // same-bh blocks share XCD (64 % 8 == 0)
    const int qt = id >> 6;
    const int b = bh >> 4, h = bh & 15;
    const size_t bh_sd = (size_t)bh * (S_LEN * HD);
    const int q0 = qt * 128 + w * 32;
    char* const plw = (char*)&PL[w][0];
    const unsigned swz = (unsigned)((lr & 7) << 4);

    v8bf qh[2][2];
#pragma unroll
    for (int mt = 0; mt < 2; ++mt)
#pragma unroll
        for (int ks = 0; ks < 2; ++ks)
            qh[mt][ks] = *reinterpret_cast<const v8bf*>(
                qb + bh_sd + (size_t)(q0 + mt * 16 + lr) * HD + ks * 32 + lg * 8);

    auto STAGE = [&](int kt, int bf) {
#pragma unroll
        for (int u = 0; u < 4; ++u) {
            int cid = w * 4 + u;          // 0..15
            const unsigned short* src;
            unsigned short* dst;
            if (cid < 8) {                // K tile
                int nt = cid >> 1, kn = cid & 1;
                src = kb + bh_sd + (size_t)(kt * 64 + nt * 16 + lr) * HD + kn * 32 + lg * 8;
                dst = &SM[bf][cid * 512];
            } else {                      // V^T tile
                int n = cid - 8;
                int nt = n >> 1, kn = n & 1;
                src = vb + bh_sd + (size_t)(nt * 16 + lr) * S_LEN + kt * 64 + kn * 32 + lg * 8;
                dst = &SM[bf][4096 + n * 512];
            }
            __builtin_amdgcn_global_load_lds(
                (const __attribute__((address_space(1))) unsigned int*)src,
                (__attribute__((address_space(3))) unsigned int*)dst, 16, 0, 0);
        }
    };

    const v4f zero4 = {0.f, 0.f, 0.f, 0.f};
    v4f O[2][4];
    float m_run[2], l_run[2];
#pragma unroll
    for (int mt = 0; mt < 2; ++mt) { m_run[mt] = -1e30f; l_run[mt] = 0.f; }
#pragma unroll
    for (int mt = 0; mt < 2; ++mt)
#pragma unroll
        for (int nt = 0; nt < 4; ++nt) O[mt][nt] = zero4;

    constexpr int NT = S_LEN / 64;

    STAGE(0, 0);
    asm volatile("s_waitcnt vmcnt(0)" ::: "memory");
    __builtin_amdgcn_s_barrier();
    __builtin_amdgcn_sched_barrier(0);

    for (int kt = 0; kt < NT; ++kt) {
        const int cur = kt & 1;
        if (kt + 1 < NT) STAGE(kt + 1, cur ^ 1);

        const unsigned short* KB = &SM[cur][0];
        const unsigned short* VT = &SM[cur][4096];

        // ---- swapped QK^T: sc[mt][nt][r] = S[kv=nt*16+lg*4+r][q=mt*16+lr] ----
        v4f sc[2][4];
#pragma unroll
        for (int mt = 0; mt < 2; ++mt)
#pragma unroll
            for (int nt = 0; nt < 4; ++nt) sc[mt][nt] = zero4;
        __builtin_amdgcn_s_setprio(1);
#pragma unroll
        for (int ks = 0; ks < 2; ++ks)
#pragma unroll
            for (int nt = 0; nt < 4; ++nt) {
                v8bf kh = *reinterpret_cast<const v8bf*>(KB + (nt * 2 + ks) * 512 + lane * 8);
#pragma unroll
                for (int mt = 0; mt < 2; ++mt)
                    sc[mt][nt] = __builtin_amdgcn_mfma_f32_16x16x32_bf16(kh, qh[mt][ks], sc[mt][nt], 0, 0, 0);
            }
        __builtin_amdgcn_s_setprio(0);

        // ---- softmax (lane-local rows; reduce over lanes {lr,+16,+32,+48}) ----
        float rm[2];
        bool need = false;
#pragma unroll
        for (int mt = 0; mt < 2; ++mt) {
            float lm = -1e30f;
#pragma unroll
            for (int nt = 0; nt < 4; ++nt)
#pragma unroll
                for (int r = 0; r < 4; ++r) lm = fmaxf(lm, sc[mt][nt][r]);
            lm = fmaxf(lm, __shfl_xor(lm, 16));
            lm = fmaxf(lm, __shfl_xor(lm, 32));
            rm[mt] = lm;
            need = need || (lm > m_run[mt] + 8.0f);
        }
        if (__any(need)) {           // defer-max (T13)
#pragma unroll
            for (int mt = 0; mt < 2; ++mt) {
                float nm = fmaxf(m_run[mt], rm[mt]);
                float alpha = __builtin_amdgcn_exp2f(m_run[mt] - nm);
                m_run[mt] = nm;
                l_run[mt] *= alpha;
                float af[4];
#pragma unroll
                for (int r = 0; r < 4; ++r) af[r] = __shfl(alpha, lg * 4 + r);
#pragma unroll
                for (int nt = 0; nt < 4; ++nt)
#pragma unroll
                    for (int r = 0; r < 4; ++r) O[mt][nt][r] *= af[r];
            }
        }
#pragma unroll
        for (int mt = 0; mt < 2; ++mt) {
            float rs = 0.f;
#pragma unroll
            for (int nt = 0; nt < 4; ++nt) {
                v4us pp;
#pragma unroll
                for (int r = 0; r < 4; ++r) {
                    float p = __builtin_amdgcn_exp2f(sc[mt][nt][r] - m_run[mt]);
                    rs += p;
                    pp[r] = cvt_bf(p);
                }
                unsigned wb = (unsigned)((mt * 16 + lr) * 128 + (nt * 16 + lg * 4) * 2) ^ swz;
                *reinterpret_cast<v4us*>(plw + wb) = pp;
            }
            rs += __shfl_xor(rs, 16);
            rs += __shfl_xor(rs, 32);
            l_run[mt] += rs;
        }
        asm volatile("s_waitcnt lgkmcnt(0)" ::: "memory");
        __builtin_amdgcn_sched_barrier(0);

        // ---- PV ----
        __builtin_amdgcn_s_setprio(1);
#pragma unroll
        for (int ks = 0; ks < 2; ++ks) {
            v8bf pa[2];
#pragma unroll
            for (int mt = 0; mt < 2; ++mt) {
                unsigned rb = (unsigned)((mt * 16 + lr) * 128 + (ks * 32 + lg * 8) * 2) ^ swz;
                pa[mt] = *reinterpret_cast<const v8bf*>(plw + rb);
            }
#pragma unroll
            for (int nt = 0; nt < 4; ++nt) {
                v8bf vf = *reinterpret_cast<const v8bf*>(VT + (nt * 2 + ks) * 512 + lane * 8);
#pragma unroll
                for (int mt = 0; mt < 2; ++mt)
                    O[mt][nt] = __builtin_amdgcn_mfma_f32_16x16x32_bf16(pa[mt], vf, O[mt][nt], 0, 0, 0);
            }
        }
        __builtin_amdgcn_s_setprio(0);

        asm volatile("s_waitcnt vmcnt(0)" ::: "memory");
        __builtin_amdgcn_s_barrier();
        __builtin_amdgcn_sched_barrier(0);
    }

    // epilogue
#pragma unroll
    for (int mt = 0; mt < 2; ++mt) {
        float linv = 1.f / l_run[mt];
#pragma unroll
        for (int r = 0; r < 4; ++r) {
            float inv = __shfl(linv, lg * 4 + r);
            int s = q0 + mt * 16 + lg * 4 + r;
            size_t base = (size_t)(b * S_LEN + s) * OUT_DIM + h * HD;
#pragma unroll
            for (int nt = 0; nt < 4; ++nt)
                avh[base + nt * 16 + lr] = cvt_bf(O[mt][nt][r] * inv);
        }
    }
}

// ---------------- Kernel 3: output projection (2-term, 128x128, 2 blocks/CU) ----------------
__global__ __launch_bounds__(256, 2)
void out_gemm_mfma(const unsigned short* __restrict__ Whi, const unsigned short* __restrict__ Wlo,
                   const unsigned short* __restrict__ Bhi, const float* __restrict__ bias,
                   float* __restrict__ out)
{
    __shared__ __align__(16) unsigned short SA[3 * 8192];
    __shared__ __align__(16) unsigned short SB[3 * 4096];
    const v4f zero4 = {0.f, 0.f, 0.f, 0.f};
    v4f acc[4][4];
#pragma unroll
    for (int i = 0; i < 4; ++i)
#pragma unroll
        for (int j = 0; j < 4; ++j) acc[i][j] = zero4;

    const int bm0 = blockIdx.x * 128;
    const int an0 = blockIdx.y * 128;
    split2_mainloop_128(Whi, Wlo, Bhi, an0, bm0, SA, SB, acc);

    const int t = threadIdx.x;
    const int lane = t & 63;
    const int w = t >> 6;
    const int wm = w >> 1, wn = w & 1;
    const int lr = lane & 15, lg = lane >> 4;
    const int nbase = an0 + wn * 64;
    const int mbase = bm0 + wm * 64;

#pragma unroll
    for (int nt = 0; nt < 4; ++nt) {
        const int n0 = nbase + nt * 16 + lg * 4;
        const float4 b4 = *reinterpret_cast<const float4*>(bias + n0);
#pragma unroll
        for (int mt = 0; mt < 4; ++mt) {
            const int m = mbase + mt * 16 + lr;
            float4 o = make_float4(acc[mt][nt][0] + b4.x, acc[mt][nt][1] + b4.y,
                                   acc[mt][nt][2] + b4.z, acc[mt][nt][3] + b4.w);
            *reinterpret_cast<float4*>(out + (size_t)m * OUT_DIM + n0) = o;
        }
    }
}

extern "C" void kernel_launch(void* const* d_in, const int* in_sizes, int n_in,
                              void* d_out, int out_size, void* d_ws, size_t ws_size,
                              hipStream_t stream)
{
    const float* x    = (const float*)d_in[0];
    const float* Wqkv = (const float*)d_in[1];
    const float* bqkv = (const float*)d_in[2];
    const float* Wo   = (const float*)d_in[3];
    const float* bo   = (const float*)d_in[4];
    float* out = (float*)d_out;

    unsigned short* p = (unsigned short*)d_ws;
    unsigned short* xhi = p;            p += BHSD;                 // 8192x1024 bf16
    unsigned short* wqh = p;            p += 3 * OUT_DIM * C_DIM;
    unsigned short* wql = p;            p += 3 * OUT_DIM * C_DIM;
    unsigned short* woh = p;            p += OUT_DIM * OUT_DIM;
    unsigned short* wol = p;            p += OUT_DIM * OUT_DIM;
    unsigned short* qb = p;             p += BHSD;
    unsigned short* kb = p;             p += BHSD;
    unsigned short* vb = p;             p += BHSD;
    unsigned short* avh = xhi;          // x dead after qkv_gemm -> reuse

    cvt_hi_kernel<<<dim3((int)(BHSD / 4 / 256)), 256, 0, stream>>>(x, xhi, (int)(BHSD / 4));
    cvt_hl_kernel<<<dim3(3 * OUT_DIM * C_DIM / 4 / 256), 256, 0, stream>>>(Wqkv, wqh, wql, 3 * OUT_DIM * C_DIM / 4);
    cvt_hl_kernel<<<dim3(OUT_DIM * C_DIM / 4 / 256), 256, 0, stream>>>(Wo, woh, wol, OUT_DIM * C_DIM / 4);

    qkv_gemm_mfma<<<dim3(64, 24), 256, 0, stream>>>(wqh, wql, xhi, bqkv, qb, kb, vb);
    attn_kernel<<<dim3(1024), 256, 0, stream>>>(qb, kb, vb, avh);
    out_gemm_mfma<<<dim3(64, 8), 256, 0, stream>>>(woh, wol, avh, bo, out);
}